// Round 12
// baseline (219.946 us; speedup 1.0000x reference)
//
#include <hip/hip_runtime.h>
#include <math.h>
#include <string.h>

#define IMG_H   512
#define IMG_W   512
#define NPIX    (IMG_H*IMG_W)       /* 262144 = 1<<18 */
#define NIMG    16
#define NSIG    5
#define MIN_SZ  200
#define SSTR    56                  /* sIn stride (dwords) */
#define SROWS   50
#define TSTR    56                  /* t stride (dwords) */
#define TSZ     (32*TSTR)           /* 1792 dwords per t array */
#define KVL     20
#define KHL     24
#define NBLK    65536               /* 2x2 blocks per image (256x256) */

typedef float f4 __attribute__((ext_vector_type(4)));

// Host-precomputed tap tables (kernarg -> s_load, off the VALU path):
//  kv[s][o][j]  = k_o[L-1-j] for j<L, 0 for j>=L (vertical, pre-reversed)
//  kh[s][o][j'] = (d<=j'<d+L) ? k_o[L-1-(j'-d)]:0 (horizontal: reversed,
//                  shifted by alignment delta d=(12-RAD)&3, zero-padded)
struct KTab {
  float kv[NSIG][3][KVL];
  float kh[NSIG][3][KHL];
  float s2[NSIG];
};

// ---------------------------------------------------------------------------
// LDS budget: t0,t1,t2 (3x1792) + sIn (50x56=2800) = 8176 dwords = 32704 B
// <= 32768 -> 4 blocks/CU (empirical: 31232B ran 4 blocks, 35328B only 3).
// t arrays are zero-initialized once: zero-weight padded taps may read
// never-written columns; they must see finite values (0*NaN hazard).
//
// Pass 1 (vertical, row-paired): thread -> (f4 col group g, output rows
//   r0=2rp, r0+1). One ds_read_b128 per tap feeds BOTH rows (row0 x w[m],
//   row1 x w[m-1] via shifted SGPR weights, zero at both ends). Reads per
//   thread: L+1 (was 2L). 24 v_fmac per read.
// Pass 2 (horizontal): P/Q ping-pong register window, 2x-unrolled chunks;
//   final dead Q-reload is guarded out; sigma1.9's zero-weight chunk1 reload
//   may read 4 dwords into the next row / past t2 into sIn (finite, dead).
// ---------------------------------------------------------------------------
template<int SIG, int RAD, int MLO, int G, int L4P>
__device__ __forceinline__ void do_sigma(const float* __restrict__ sIn,
                                         float* __restrict__ t0,
                                         float* __restrict__ t1,
                                         float* __restrict__ t2,
                                         const KTab& kt, int tid, float* fr)
{
  constexpr int L = 2*RAD + 1;

  // ---- pass 1: vertical conv -> t0(k0), t1(k1), t2(k2) ----
  if (tid < 16*G) {
    int g  = tid % G;                  // column group (compile-time magic div)
    int rp = tid / G;
    int r0 = rp*2;
    int a  = (r0 + 9 - RAD)*SSTR + 4*(MLO + g);
    f4 a00={0,0,0,0}, a01={0,0,0,0}, a02={0,0,0,0};
    f4 a10={0,0,0,0}, a11={0,0,0,0}, a12={0,0,0,0};
    float w0c=0.0f, w1c=0.0f, w2c=0.0f;
#pragma unroll 1
    for (int m = 0; m <= L; ++m) {     // L+1 iterations
      float w0p=w0c, w1p=w1c, w2p=w2c;
      w0c = kt.kv[SIG][0][m];          // kv[L]==0 (pad) on final iteration
      w1c = kt.kv[SIG][1][m];
      w2c = kt.kv[SIG][2][m];
      f4 x = *(const f4*)(sIn + a); a += SSTR;
      a00 += x*w0c; a01 += x*w1c; a02 += x*w2c;   // row r0,   tap j=m
      a10 += x*w0p; a11 += x*w1p; a12 += x*w2p;   // row r0+1, tap j=m-1
    }
    int tb = r0*TSTR + 4*(MLO + g);
    *(f4*)(t0+tb)      = a00; *(f4*)(t1+tb)      = a01; *(f4*)(t2+tb)      = a02;
    *(f4*)(t0+tb+TSTR) = a10; *(f4*)(t1+tb+TSTR) = a11; *(f4*)(t2+tb+TSTR) = a12;
  }
  __syncthreads();

  // ---- pass 2: horizontal conv + vesselness ----
  {
    int r  = tid >> 3;
    int c0 = (tid & 7) * 4;
    int wa = r*TSTR + 4*MLO + c0;
    f4 P0 = *(const f4*)(t0 + wa);
    f4 P1 = *(const f4*)(t1 + wa);
    f4 P2 = *(const f4*)(t2 + wa);
    f4 Q0 = *(const f4*)(t0 + wa + 4);
    f4 Q1 = *(const f4*)(t1 + wa + 4);
    f4 Q2 = *(const f4*)(t2 + wa + 4);
    wa += 8;
    f4 hrr={0,0,0,0}, hrc={0,0,0,0}, hcc={0,0,0,0};
#pragma unroll 1
    for (int aa = 0; aa < L4P/8; ++aa) {
      {  // chunk 2aa: low=P, high=Q ; then P <- next group (always consumed)
        f4 w0 = *(const f4*)&kt.kh[SIG][0][8*aa];
        f4 w1 = *(const f4*)&kt.kh[SIG][1][8*aa];
        f4 w2 = *(const f4*)&kt.kh[SIG][2][8*aa];
#pragma unroll
        for (int b = 0; b < 4; ++b)
#pragma unroll
          for (int k = 0; k < 4; ++k) {
            int e = b + k;
            float x2 = (e < 4) ? P2[e] : Q2[e-4];
            float x1 = (e < 4) ? P1[e] : Q1[e-4];
            float x0 = (e < 4) ? P0[e] : Q0[e-4];
            hrr[k] += x2 * w0[b];                // Hrr = vert k2 (.) horiz k0
            hrc[k] += x1 * w1[b];                // Hrc = vert k1 (.) horiz k1
            hcc[k] += x0 * w2[b];                // Hcc = vert k0 (.) horiz k2
          }
        P0 = *(const f4*)(t0 + wa);
        P1 = *(const f4*)(t1 + wa);
        P2 = *(const f4*)(t2 + wa);
      }
      {  // chunk 2aa+1: low=Q, high=P(new) ; Q-reload dead on last iter
        f4 w0 = *(const f4*)&kt.kh[SIG][0][8*aa+4];
        f4 w1 = *(const f4*)&kt.kh[SIG][1][8*aa+4];
        f4 w2 = *(const f4*)&kt.kh[SIG][2][8*aa+4];
#pragma unroll
        for (int b = 0; b < 4; ++b)
#pragma unroll
          for (int k = 0; k < 4; ++k) {
            int e = b + k;
            float x2 = (e < 4) ? Q2[e] : P2[e-4];
            float x1 = (e < 4) ? Q1[e] : P1[e-4];
            float x0 = (e < 4) ? Q0[e] : P0[e-4];
            hrr[k] += x2 * w0[b];
            hrc[k] += x1 * w1[b];
            hcc[k] += x0 * w2[b];
          }
        if (aa + 1 < L4P/8) {
          Q0 = *(const f4*)(t0 + wa + 4);
          Q1 = *(const f4*)(t1 + wa + 4);
          Q2 = *(const f4*)(t2 + wa + 4);
        }
      }
      wa += 8;
    }
    float s2v = kt.s2[SIG];
#pragma unroll
    for (int k = 0; k < 4; ++k) {
      float Hrr = hrr[k]*s2v, Hrc = hrc[k]*s2v, Hcc = hcc[k]*s2v;
      float mid  = 0.5f*(Hrr + Hcc);
      float dif  = 0.5f*(Hrr - Hcc);
      float disc = sqrtf(dif*dif + Hrc*Hrc);
      float ehi  = mid + disc;
      float elo  = mid - disc;
      bool  sm   = fabsf(ehi) <= fabsf(elo);
      float lam1 = sm ? ehi : elo;
      float lam2 = sm ? elo : ehi;
      float lam2c = fmaxf(lam2, 1e-10f);
      float q    = lam1 / lam2c;
      float rb2  = q*q;
      float ssq  = lam1*lam1 + lam2*lam2;
      float v    = expf((-rb2)/2.0f) * (1.0f - expf((-ssq)/50.0f));
      fr[k] = fmaxf(fr[k], v);
    }
  }
  __syncthreads();
}

__global__ __launch_bounds__(256)
void frangi_label_kernel(const float* __restrict__ img,
                         int* __restrict__ labels,
                         int* __restrict__ parent,
                         int* __restrict__ bsizes,
                         KTab kt)
{
  __shared__ float lds[3*TSZ + SROWS*SSTR];   // 8176 dwords = 32704 B
  float* t0  = lds;
  float* t1  = lds + TSZ;
  float* t2  = lds + 2*TSZ;
  float* sIn = lds + 3*TSZ;

  const int tid    = threadIdx.x;
  const int imgIdx = blockIdx.y;
  const int tIdx   = blockIdx.x;
  const int tr0    = (tIdx >> 4) * 32;
  const int tc0    = (tIdx & 15) * 32;
  const float* __restrict__ im = img + (size_t)imgIdx * NPIX;

  // zero t region (finite values under zero-weight padded-tap reads)
  for (int i = tid; i < 3*TSZ; i += 256) lds[i] = 0.0f;
  // fill sIn: zeros outside cs [3,53); reflect('symmetric') + negate/scale.
  for (int idx = tid; idx < SROWS*64; idx += 256) {
    int r  = idx >> 6;
    int cs = idx & 63;
    if (cs < SSTR) {
      float v = 0.0f;
      if (cs >= 3 && cs < 53) {
        int gr = tr0 + r - 9;
        int gc = tc0 + cs - 12;
        gr = (gr < 0) ? (-1 - gr) : ((gr >= IMG_H) ? (2*IMG_H - 1 - gr) : gr);
        gc = (gc < 0) ? (-1 - gc) : ((gc >= IMG_W) ? (2*IMG_W - 1 - gc) : gc);
        v = -(im[gr*IMG_W + gc] * 500.0f);
      }
      sIn[r*SSTR + cs] = v;
    }
  }
  __syncthreads();

  float fr[4] = {0.0f, 0.0f, 0.0f, 0.0f};
  //        SIG RAD MLO  G L4P
  do_sigma<0,  4,  2, 12, 16>(sIn, t0, t1, t2, kt, tid, fr);  // s=1.0,L=9
  do_sigma<1,  5,  1, 12, 16>(sIn, t0, t1, t2, kt, tid, fr);  // s=1.3,L=11
  do_sigma<2,  6,  1, 12, 16>(sIn, t0, t1, t2, kt, tid, fr);  // s=1.6,L=13
  do_sigma<3,  8,  1, 13, 24>(sIn, t0, t1, t2, kt, tid, fr);  // s=1.9,L=17
  do_sigma<4,  9,  0, 14, 24>(sIn, t0, t1, t2, kt, tid, fr);  // s=2.2,L=19

  const int r  = tid >> 3;
  const int c0 = (tid & 7) * 4;
  const int gr = tr0 + r;
  const size_t imgBase = (size_t)imgIdx * NPIX;
#pragma unroll
  for (int k = 0; k < 4; ++k) {
    int p = gr*IMG_W + tc0 + c0 + k;
    float x = im[p];
    bool m = (x >= 0.1f) && (x <= 0.5f) && (fr[k] >= 0.2f);
    labels[imgBase + p] = m ? p : -1;
  }
  // init 2x2-block UF arrays: thread t <-> one of the 256 tile blocks
  {
    int blk = (tr0/2 + (tid >> 4))*256 + (tc0/2 + (tid & 15));
    int o   = (imgIdx << 16) + blk;
    parent[o] = blk;
    bsizes[o] = 0;
  }
}

// ---------------------------------------------------------------------------
// BUF: 8-connected CCL over 2x2 blocks (all 4 px of a block are mutually
// 8-adjacent, so block-level UF yields exactly the pixel components).
// ---------------------------------------------------------------------------
__device__ __forceinline__ int ldA(const int* p) {
  return __hip_atomic_load(p, __ATOMIC_RELAXED, __HIP_MEMORY_SCOPE_AGENT);
}
__device__ __forceinline__ int rootOf(const int* L, int x) {
  int pa = ldA(&L[x]);
  while (pa != x) { int g = ldA(&L[pa]); x = pa; pa = g; }
  return x;
}
__device__ __forceinline__ void unite(int* P, int a, int b) {
  while (true) {
    a = rootOf(P, a);
    b = rootOf(P, b);
    if (a == b) return;
    int hi = a > b ? a : b;
    int lo = a ^ b ^ hi;
    int old = atomicCAS(&P[hi], hi, lo);
    if (old == hi) return;
    a = old; b = lo;
  }
}

__global__ __launch_bounds__(256)
void merge_kernel(const int* __restrict__ labels, int* __restrict__ parent)
{
  int gid = blockIdx.x*256 + threadIdx.x;      // one thread per 2x2 block
  int img = gid >> 16;
  int blk = gid & (NBLK - 1);
  int BR = blk >> 8, BC = blk & 255;
  const int* L = labels + ((size_t)img << 18);
  int p = BR*1024 + BC*2;                      // top-left pixel of block
  int2 t = *(const int2*)(L + p);              // l00,l01
  int2 bm = *(const int2*)(L + p + 512);       // l10,l11
  bool f00 = t.x >= 0, f01 = t.y >= 0, f10 = bm.x >= 0, f11 = bm.y >= 0;
  if (!(f00 | f01 | f10 | f11)) return;
  int* P = parent + (img << 16);
  // W: our left col vs their right col (all cross pairs are 8-adjacent)
  if (BC > 0 && (f00 | f10) && (L[p-1] >= 0 || L[p+511] >= 0))
    unite(P, blk, blk-1);
  if (BR > 0) {
    int2 n = *(const int2*)(L + p - 512);      // their bottom row
    if ((f00 | f01) && (n.x >= 0 || n.y >= 0)) unite(P, blk, blk-256);
    if (BC > 0   && f00 && L[p-513] >= 0)      unite(P, blk, blk-257);
    if (BC < 255 && f01 && L[p-510] >= 0)      unite(P, blk, blk-255);
  }
}

// compress block roots + accumulate component pixel counts.
// Wave segmented scan (flag-propagating) -> ~1 atomic per run.
__global__ __launch_bounds__(256)
void compress_count_kernel(const int* __restrict__ labels,
                           int* __restrict__ parent, int* __restrict__ bsizes)
{
  int gid = blockIdx.x*256 + threadIdx.x;
  int img = gid >> 16;
  int blk = gid & (NBLK - 1);
  int BR = blk >> 8, BC = blk & 255;
  const int* L = labels + ((size_t)img << 18);
  int p = BR*1024 + BC*2;
  int2 t = *(const int2*)(L + p);
  int2 bm = *(const int2*)(L + p + 512);
  int cnt = (t.x >= 0) + (t.y >= 0) + (bm.x >= 0) + (bm.y >= 0);
  int* P = parent + (img << 16);
  int rt = -1;
  if (cnt) {
    rt = rootOf(P, blk);
    __hip_atomic_store(&P[blk], rt, __ATOMIC_RELAXED, __HIP_MEMORY_SCOPE_AGENT);
  }
  int lane = threadIdx.x & 63;
  int val  = cnt;
  int prt  = __shfl_up(rt, 1);
  int fseg = (lane == 0 || prt != rt) ? 1 : 0;
#pragma unroll
  for (int d = 1; d < 64; d <<= 1) {
    int v2  = __shfl_up(val, d);
    int fg2 = __shfl_up(fseg, d);
    if (lane >= d && !fseg) { val += v2; fseg |= fg2; }
  }
  int nrt = __shfl_down(rt, 1);
  bool tail = (lane == 63) || (nrt != rt);
  if (tail && rt >= 0)
    atomicAdd(&bsizes[(img << 16) + rt], val);
}

__global__ __launch_bounds__(256)
void output_kernel(const int* __restrict__ labels, const int* __restrict__ parent,
                   const int* __restrict__ bsizes, float* __restrict__ out)
{
  int qid = blockIdx.x*256 + threadIdx.x;      // 4 px in a row = 2 blocks
  int img = qid >> 16;
  int p0  = (qid & 65535) << 2;
  const int* L = labels + ((size_t)img << 18);
  int4 l4 = *(const int4*)(L + p0);
  int r = p0 >> 9, c = p0 & 511;
  int blk0 = (r >> 1)*256 + (c >> 1);
  const int* P = parent + (img << 16);
  const int* S = bsizes + (img << 16);
  int2 pp = *(const int2*)(P + blk0);
  float4 o;
  o.x = (l4.x >= 0 && S[pp.x] >= MIN_SZ) ? 1.0f : 0.0f;
  o.y = (l4.y >= 0 && S[pp.x] >= MIN_SZ) ? 1.0f : 0.0f;
  o.z = (l4.z >= 0 && S[pp.y] >= MIN_SZ) ? 1.0f : 0.0f;
  o.w = (l4.w >= 0 && S[pp.y] >= MIN_SZ) ? 1.0f : 0.0f;
  *(float4*)(out + ((size_t)qid << 2)) = o;
}

// ---------------------------------------------------------------------------
// Host: scipy.ndimage-style Gaussian derivative kernels (truncate=4).
// ---------------------------------------------------------------------------
static void gauss1d(double sigma, int order, int rad, float* out)
{
  int L = 2*rad + 1;
  double phi[24];
  double s = 0.0;
  for (int i = 0; i < L; ++i) {
    double x = (double)(i - rad);
    phi[i] = exp(-0.5*x*x/(sigma*sigma));
    s += phi[i];
  }
  for (int i = 0; i < L; ++i) phi[i] /= s;
  if (order == 0) {
    for (int i = 0; i < L; ++i) out[i] = (float)phi[i];
    return;
  }
  double q[3] = {1.0, 0.0, 0.0};
  for (int it = 0; it < order; ++it) {
    double nq[3] = {0.0, 0.0, 0.0};
    for (int i = 0; i <= order; ++i) {
      double v = 0.0;
      if (i+1 <= order) v += (double)(i+1) * q[i+1];
      if (i-1 >= 0)     v += (-1.0/(sigma*sigma)) * q[i-1];
      nq[i] = v;
    }
    q[0] = nq[0]; q[1] = nq[1]; q[2] = nq[2];
  }
  for (int i = 0; i < L; ++i) {
    double x = (double)(i - rad);
    double poly = q[0];
    double xp = x;
    for (int e = 1; e <= order; ++e) { poly += xp*q[e]; xp *= x; }
    out[i] = (float)(poly*phi[i]);
  }
}

extern "C" void kernel_launch(void* const* d_in, const int* in_sizes, int n_in,
                              void* d_out, int out_size, void* d_ws, size_t ws_size,
                              hipStream_t stream)
{
  (void)in_sizes; (void)n_in; (void)out_size; (void)ws_size;
  const float* img = (const float*)d_in[0];
  float* out = (float*)d_out;
  // ws: labels 16MB | parent 4MB | bsizes 4MB
  int* labels = (int*)d_ws;
  int* parent = labels + (size_t)NIMG * NPIX;
  int* bsizes = parent + (size_t)NIMG * NBLK;

  KTab kt;
  memset(&kt, 0, sizeof(kt));
  for (int s = 0; s < NSIG; ++s) {
    double sigma = 1.0 + 0.3 * (double)s;
    int rad = (int)(4.0 * sigma + 0.5);        // 4,5,6,8,9
    int L   = 2*rad + 1;
    int dlt = (12 - rad) & 3;
    kt.s2[s] = (float)(sigma * sigma);
    float k[3][24];
    for (int o = 0; o < 3; ++o) gauss1d(sigma, o, rad, k[o]);
    for (int o = 0; o < 3; ++o) {
      for (int j = 0; j < L; ++j)
        kt.kv[s][o][j] = k[o][L-1-j];          // kv[L..] stay 0 (pad)
      for (int jp = 0; jp < KHL; ++jp)
        kt.kh[s][o][jp] = (jp >= dlt && jp - dlt < L) ? k[o][L-1-(jp-dlt)] : 0.0f;
    }
  }

  dim3 gridF(NPIX / (32*32), NIMG);            // 256 tiles x 16 images
  frangi_label_kernel<<<gridF, 256, 0, stream>>>(img, labels, parent, bsizes, kt);

  int bblocks = (NIMG * NBLK) / 256;           // 4096 (1 thread / 2x2 block)
  merge_kernel         <<<bblocks, 256, 0, stream>>>(labels, parent);
  compress_count_kernel<<<bblocks, 256, 0, stream>>>(labels, parent, bsizes);
  output_kernel        <<<bblocks, 256, 0, stream>>>(labels, parent, bsizes, out);
}

// Round 13
// 206.537 us; speedup vs baseline: 1.0649x; 1.0649x over previous
//
#include <hip/hip_runtime.h>
#include <math.h>
#include <string.h>

#define IMG_H   512
#define IMG_W   512
#define NPIX    (IMG_H*IMG_W)       /* 262144 = 1<<18 */
#define NIMG    16
#define NSIG    5
#define MIN_SZ  200
#define SSTR    60                  /* sIn stride (dwords) */
#define SROWS   52                  /* 50 data rows + 2 zero rows for tap pad */
#define TSTR    68                  /* t stride (dwords): room for tail prefetch */
#define KVL     20
#define KHL     24
#define NBLK    65536               /* 2x2 blocks per image (256x256) */

typedef float f4 __attribute__((ext_vector_type(4)));

// Host-precomputed tap tables (kernarg -> s_load, off the VALU path):
//  kv[s][o][j]  = k_o[L-1-j], zero-padded to LP4 (vertical, pre-reversed)
//  kh[s][o][j'] = (d<=j'<d+L) ? k_o[L-1-(j'-d)]:0 (horizontal: reversed,
//                  shifted by alignment delta d=(12-RAD)&3, zero-padded)
struct KTab {
  float kv[NSIG][3][KVL];
  float kh[NSIG][3][KHL];
  float s2[NSIG];
};

// ---------------------------------------------------------------------------
// Round-9 proven conv structure (157 us frangi; best of 12 rounds):
// Pass 1 (vertical): threads tid < 32*GH own (row r0, 8-col pair slot).
//   4-tap chunks: 3x s_load_dwordx4 weights + 8x ds_read_b128 + 96 FMA per
//   chunk -> one lgkm weight-wait amortized over 96 FMAs.
// Pass 2 (horizontal): P/Q ping-pong register window, 2x-unrolled chunks,
//   all register roles compile-time. Tail prefetch reads dead in-row data.
// ---------------------------------------------------------------------------
template<int SIG, int RAD, int MLO, int GH, int LP4, int L4P>
__device__ __forceinline__ void do_sigma(const float* __restrict__ sIn,
                                         float* __restrict__ t0,
                                         float* __restrict__ t1,
                                         float* __restrict__ t2,
                                         const KTab& kt, int tid, float* fr)
{
  // ---- pass 1: vertical conv -> t0(k0), t1(k1), t2(k2) ----
  if (tid < 32*GH) {
    int r0 = tid & 31;
    int h  = tid >> 5;                 // 8-col pair slot
    int a  = (r0 + 9 - RAD)*SSTR + 4*(MLO + 2*h);
    f4 A0={0,0,0,0}, A1={0,0,0,0}, A2={0,0,0,0};
    f4 B0={0,0,0,0}, B1={0,0,0,0}, B2={0,0,0,0};
#pragma unroll 1
    for (int jj = 0; jj < LP4/4; ++jj) {
      f4 w0 = *(const f4*)&kt.kv[SIG][0][4*jj];
      f4 w1 = *(const f4*)&kt.kv[SIG][1][4*jj];
      f4 w2 = *(const f4*)&kt.kv[SIG][2][4*jj];
#pragma unroll
      for (int u = 0; u < 4; ++u) {
        f4 xA = *(const f4*)(sIn + a);
        f4 xB = *(const f4*)(sIn + a + 4);
        a += SSTR;
        A0 += xA*w0[u]; A1 += xA*w1[u]; A2 += xA*w2[u];
        B0 += xB*w0[u]; B1 += xB*w1[u]; B2 += xB*w2[u];
      }
    }
    int tb = r0*TSTR + 4*(MLO + 2*h);
    *(f4*)(t0 + tb)     = A0; *(f4*)(t1 + tb)     = A1; *(f4*)(t2 + tb)     = A2;
    *(f4*)(t0 + tb + 4) = B0; *(f4*)(t1 + tb + 4) = B1; *(f4*)(t2 + tb + 4) = B2;
  }
  __syncthreads();

  // ---- pass 2: horizontal conv + vesselness ----
  {
    int r  = tid >> 3;
    int c0 = (tid & 7) * 4;
    int wa = r*TSTR + 4*MLO + c0;
    f4 P0 = *(const f4*)(t0 + wa);
    f4 P1 = *(const f4*)(t1 + wa);
    f4 P2 = *(const f4*)(t2 + wa);
    f4 Q0 = *(const f4*)(t0 + wa + 4);
    f4 Q1 = *(const f4*)(t1 + wa + 4);
    f4 Q2 = *(const f4*)(t2 + wa + 4);
    wa += 8;
    f4 hrr={0,0,0,0}, hrc={0,0,0,0}, hcc={0,0,0,0};
#pragma unroll 1
    for (int aa = 0; aa < L4P/8; ++aa) {
      {  // chunk 2aa: low=P, high=Q ; then P <- next group
        f4 w0 = *(const f4*)&kt.kh[SIG][0][8*aa];
        f4 w1 = *(const f4*)&kt.kh[SIG][1][8*aa];
        f4 w2 = *(const f4*)&kt.kh[SIG][2][8*aa];
#pragma unroll
        for (int b = 0; b < 4; ++b)
#pragma unroll
          for (int k = 0; k < 4; ++k) {
            int e = b + k;                       // compile-time under unroll
            float x2 = (e < 4) ? P2[e] : Q2[e-4];
            float x1 = (e < 4) ? P1[e] : Q1[e-4];
            float x0 = (e < 4) ? P0[e] : Q0[e-4];
            hrr[k] += x2 * w0[b];                // Hrr = vert k2 (.) horiz k0
            hrc[k] += x1 * w1[b];                // Hrc = vert k1 (.) horiz k1
            hcc[k] += x0 * w2[b];                // Hcc = vert k0 (.) horiz k2
          }
        P0 = *(const f4*)(t0 + wa);
        P1 = *(const f4*)(t1 + wa);
        P2 = *(const f4*)(t2 + wa);
      }
      {  // chunk 2aa+1: low=Q, high=P(new) ; then Q <- next group
        f4 w0 = *(const f4*)&kt.kh[SIG][0][8*aa+4];
        f4 w1 = *(const f4*)&kt.kh[SIG][1][8*aa+4];
        f4 w2 = *(const f4*)&kt.kh[SIG][2][8*aa+4];
#pragma unroll
        for (int b = 0; b < 4; ++b)
#pragma unroll
          for (int k = 0; k < 4; ++k) {
            int e = b + k;
            float x2 = (e < 4) ? Q2[e] : P2[e-4];
            float x1 = (e < 4) ? Q1[e] : P1[e-4];
            float x0 = (e < 4) ? Q0[e] : P0[e-4];
            hrr[k] += x2 * w0[b];
            hrc[k] += x1 * w1[b];
            hcc[k] += x0 * w2[b];
          }
        Q0 = *(const f4*)(t0 + wa + 4);
        Q1 = *(const f4*)(t1 + wa + 4);
        Q2 = *(const f4*)(t2 + wa + 4);
      }
      wa += 8;
    }
    float s2v = kt.s2[SIG];
#pragma unroll
    for (int k = 0; k < 4; ++k) {
      float Hrr = hrr[k]*s2v, Hrc = hrc[k]*s2v, Hcc = hcc[k]*s2v;
      float mid  = 0.5f*(Hrr + Hcc);
      float dif  = 0.5f*(Hrr - Hcc);
      float disc = sqrtf(dif*dif + Hrc*Hrc);
      float ehi  = mid + disc;
      float elo  = mid - disc;
      bool  sm   = fabsf(ehi) <= fabsf(elo);
      float lam1 = sm ? ehi : elo;
      float lam2 = sm ? elo : ehi;
      float lam2c = fmaxf(lam2, 1e-10f);
      float q    = lam1 / lam2c;
      float rb2  = q*q;
      float ssq  = lam1*lam1 + lam2*lam2;
      float v    = expf((-rb2)/2.0f) * (1.0f - expf((-ssq)/50.0f));
      fr[k] = fmaxf(fr[k], v);
    }
  }
  __syncthreads();                     // t arrays free for next sigma
}

__global__ __launch_bounds__(256)
void frangi_label_kernel(const float* __restrict__ img,
                         int* __restrict__ labels,
                         int* __restrict__ parent,
                         int* __restrict__ bsizes,
                         KTab kt)
{
  __shared__ float sIn[SROWS*SSTR];    // 12480 B
  __shared__ float t0[32*TSTR];        // 8704 B x3
  __shared__ float t1[32*TSTR];
  __shared__ float t2[32*TSTR];

  const int tid    = threadIdx.x;
  const int imgIdx = blockIdx.y;
  const int tIdx   = blockIdx.x;
  const int tr0    = (tIdx >> 4) * 32;
  const int tc0    = (tIdx & 15) * 32;
  const float* __restrict__ im = img + (size_t)imgIdx * NPIX;

  // fill sIn: zeros outside rows [0,50) x cs [3,53);
  // inside: reflect('symmetric') + negate/scale.
  for (int idx = tid; idx < SROWS*64; idx += 256) {
    int r  = idx >> 6;
    int cs = idx & 63;
    if (cs < SSTR) {
      float v = 0.0f;
      if (r < 50 && cs >= 3 && cs < 53) {
        int gr = tr0 + r - 9;
        int gc = tc0 + cs - 12;
        gr = (gr < 0) ? (-1 - gr) : ((gr >= IMG_H) ? (2*IMG_H - 1 - gr) : gr);
        gc = (gc < 0) ? (-1 - gc) : ((gc >= IMG_W) ? (2*IMG_W - 1 - gc) : gc);
        v = -(im[gr*IMG_W + gc] * 500.0f);
      }
      sIn[r*SSTR + cs] = v;
    }
  }
  __syncthreads();

  float fr[4] = {0.0f, 0.0f, 0.0f, 0.0f};
  //        SIG RAD MLO GH LP4 L4P
  do_sigma<0,  4,  2,  6, 12, 16>(sIn, t0, t1, t2, kt, tid, fr);  // s=1.0,L=9
  do_sigma<1,  5,  1,  6, 12, 16>(sIn, t0, t1, t2, kt, tid, fr);  // s=1.3,L=11
  do_sigma<2,  6,  1,  6, 16, 16>(sIn, t0, t1, t2, kt, tid, fr);  // s=1.6,L=13
  do_sigma<3,  8,  1,  7, 20, 24>(sIn, t0, t1, t2, kt, tid, fr);  // s=1.9,L=17
  do_sigma<4,  9,  0,  7, 20, 24>(sIn, t0, t1, t2, kt, tid, fr);  // s=2.2,L=19

  const int r  = tid >> 3;
  const int c0 = (tid & 7) * 4;
  const int gr = tr0 + r;
  const size_t imgBase = (size_t)imgIdx * NPIX;
#pragma unroll
  for (int k = 0; k < 4; ++k) {
    int p = gr*IMG_W + tc0 + c0 + k;
    float x = im[p];
    bool m = (x >= 0.1f) && (x <= 0.5f) && (fr[k] >= 0.2f);
    labels[imgBase + p] = m ? p : -1;
  }
  // init 2x2-block UF arrays: thread t <-> one of the 256 tile blocks
  {
    int blk = (tr0/2 + (tid >> 4))*256 + (tc0/2 + (tid & 15));
    int o   = (imgIdx << 16) + blk;
    parent[o] = blk;
    bsizes[o] = 0;
  }
}

// ---------------------------------------------------------------------------
// BUF: 8-connected CCL over 2x2 blocks (all 4 px of a block are mutually
// 8-adjacent, so block-level UF yields exactly the pixel components).
// ---------------------------------------------------------------------------
__device__ __forceinline__ int ldA(const int* p) {
  return __hip_atomic_load(p, __ATOMIC_RELAXED, __HIP_MEMORY_SCOPE_AGENT);
}
__device__ __forceinline__ int rootOf(const int* L, int x) {
  int pa = ldA(&L[x]);
  while (pa != x) { int g = ldA(&L[pa]); x = pa; pa = g; }
  return x;
}
__device__ __forceinline__ void unite(int* P, int a, int b) {
  while (true) {
    a = rootOf(P, a);
    b = rootOf(P, b);
    if (a == b) return;
    int hi = a > b ? a : b;
    int lo = a ^ b ^ hi;
    int old = atomicCAS(&P[hi], hi, lo);
    if (old == hi) return;
    a = old; b = lo;
  }
}

__global__ __launch_bounds__(256)
void merge_kernel(const int* __restrict__ labels, int* __restrict__ parent)
{
  int gid = blockIdx.x*256 + threadIdx.x;      // one thread per 2x2 block
  int img = gid >> 16;
  int blk = gid & (NBLK - 1);
  int BR = blk >> 8, BC = blk & 255;
  const int* L = labels + ((size_t)img << 18);
  int p = BR*1024 + BC*2;                      // top-left pixel of block
  int2 t = *(const int2*)(L + p);              // l00,l01
  int2 bm = *(const int2*)(L + p + 512);       // l10,l11
  bool f00 = t.x >= 0, f01 = t.y >= 0, f10 = bm.x >= 0, f11 = bm.y >= 0;
  if (!(f00 | f01 | f10 | f11)) return;
  int* P = parent + (img << 16);
  // W: our left col vs their right col (all cross pairs are 8-adjacent)
  if (BC > 0 && (f00 | f10) && (L[p-1] >= 0 || L[p+511] >= 0))
    unite(P, blk, blk-1);
  if (BR > 0) {
    int2 n = *(const int2*)(L + p - 512);      // their bottom row
    if ((f00 | f01) && (n.x >= 0 || n.y >= 0)) unite(P, blk, blk-256);
    if (BC > 0   && f00 && L[p-513] >= 0)      unite(P, blk, blk-257);
    if (BC < 255 && f01 && L[p-510] >= 0)      unite(P, blk, blk-255);
  }
}

// compress block roots + accumulate component pixel counts.
// Wave segmented scan (flag-propagating) -> ~1 atomic per run.
__global__ __launch_bounds__(256)
void compress_count_kernel(const int* __restrict__ labels,
                           int* __restrict__ parent, int* __restrict__ bsizes)
{
  int gid = blockIdx.x*256 + threadIdx.x;
  int img = gid >> 16;
  int blk = gid & (NBLK - 1);
  int BR = blk >> 8, BC = blk & 255;
  const int* L = labels + ((size_t)img << 18);
  int p = BR*1024 + BC*2;
  int2 t = *(const int2*)(L + p);
  int2 bm = *(const int2*)(L + p + 512);
  int cnt = (t.x >= 0) + (t.y >= 0) + (bm.x >= 0) + (bm.y >= 0);
  int* P = parent + (img << 16);
  int rt = -1;
  if (cnt) {
    rt = rootOf(P, blk);
    __hip_atomic_store(&P[blk], rt, __ATOMIC_RELAXED, __HIP_MEMORY_SCOPE_AGENT);
  }
  int lane = threadIdx.x & 63;
  int val  = cnt;
  int prt  = __shfl_up(rt, 1);
  int fseg = (lane == 0 || prt != rt) ? 1 : 0;
#pragma unroll
  for (int d = 1; d < 64; d <<= 1) {
    int v2  = __shfl_up(val, d);
    int fg2 = __shfl_up(fseg, d);
    if (lane >= d && !fseg) { val += v2; fseg |= fg2; }
  }
  int nrt = __shfl_down(rt, 1);
  bool tail = (lane == 63) || (nrt != rt);
  if (tail && rt >= 0)
    atomicAdd(&bsizes[(img << 16) + rt], val);
}

__global__ __launch_bounds__(256)
void output_kernel(const int* __restrict__ labels, const int* __restrict__ parent,
                   const int* __restrict__ bsizes, float* __restrict__ out)
{
  int qid = blockIdx.x*256 + threadIdx.x;      // 4 px in a row = 2 blocks
  int img = qid >> 16;
  int p0  = (qid & 65535) << 2;
  const int* L = labels + ((size_t)img << 18);
  int4 l4 = *(const int4*)(L + p0);
  int r = p0 >> 9, c = p0 & 511;
  int blk0 = (r >> 1)*256 + (c >> 1);
  const int* P = parent + (img << 16);
  const int* S = bsizes + (img << 16);
  int2 pp = *(const int2*)(P + blk0);
  float4 o;
  o.x = (l4.x >= 0 && S[pp.x] >= MIN_SZ) ? 1.0f : 0.0f;
  o.y = (l4.y >= 0 && S[pp.x] >= MIN_SZ) ? 1.0f : 0.0f;
  o.z = (l4.z >= 0 && S[pp.y] >= MIN_SZ) ? 1.0f : 0.0f;
  o.w = (l4.w >= 0 && S[pp.y] >= MIN_SZ) ? 1.0f : 0.0f;
  *(float4*)(out + ((size_t)qid << 2)) = o;
}

// ---------------------------------------------------------------------------
// Host: scipy.ndimage-style Gaussian derivative kernels (truncate=4).
// ---------------------------------------------------------------------------
static void gauss1d(double sigma, int order, int rad, float* out)
{
  int L = 2*rad + 1;
  double phi[24];
  double s = 0.0;
  for (int i = 0; i < L; ++i) {
    double x = (double)(i - rad);
    phi[i] = exp(-0.5*x*x/(sigma*sigma));
    s += phi[i];
  }
  for (int i = 0; i < L; ++i) phi[i] /= s;
  if (order == 0) {
    for (int i = 0; i < L; ++i) out[i] = (float)phi[i];
    return;
  }
  double q[3] = {1.0, 0.0, 0.0};
  for (int it = 0; it < order; ++it) {
    double nq[3] = {0.0, 0.0, 0.0};
    for (int i = 0; i <= order; ++i) {
      double v = 0.0;
      if (i+1 <= order) v += (double)(i+1) * q[i+1];
      if (i-1 >= 0)     v += (-1.0/(sigma*sigma)) * q[i-1];
      nq[i] = v;
    }
    q[0] = nq[0]; q[1] = nq[1]; q[2] = nq[2];
  }
  for (int i = 0; i < L; ++i) {
    double x = (double)(i - rad);
    double poly = q[0];
    double xp = x;
    for (int e = 1; e <= order; ++e) { poly += xp*q[e]; xp *= x; }
    out[i] = (float)(poly*phi[i]);
  }
}

extern "C" void kernel_launch(void* const* d_in, const int* in_sizes, int n_in,
                              void* d_out, int out_size, void* d_ws, size_t ws_size,
                              hipStream_t stream)
{
  (void)in_sizes; (void)n_in; (void)out_size; (void)ws_size;
  const float* img = (const float*)d_in[0];
  float* out = (float*)d_out;
  // ws: labels 16MB | parent 4MB | bsizes 4MB
  int* labels = (int*)d_ws;
  int* parent = labels + (size_t)NIMG * NPIX;
  int* bsizes = parent + (size_t)NIMG * NBLK;

  KTab kt;
  memset(&kt, 0, sizeof(kt));
  for (int s = 0; s < NSIG; ++s) {
    double sigma = 1.0 + 0.3 * (double)s;
    int rad = (int)(4.0 * sigma + 0.5);        // 4,5,6,8,9
    int L   = 2*rad + 1;
    int dlt = (12 - rad) & 3;
    kt.s2[s] = (float)(sigma * sigma);
    float k[3][24];
    for (int o = 0; o < 3; ++o) gauss1d(sigma, o, rad, k[o]);
    for (int o = 0; o < 3; ++o) {
      for (int j = 0; j < L; ++j)
        kt.kv[s][o][j] = k[o][L-1-j];          // kv[L..] stay 0 (pad)
      for (int jp = 0; jp < KHL; ++jp)
        kt.kh[s][o][jp] = (jp >= dlt && jp - dlt < L) ? k[o][L-1-(jp-dlt)] : 0.0f;
    }
  }

  dim3 gridF(NPIX / (32*32), NIMG);            // 256 tiles x 16 images
  frangi_label_kernel<<<gridF, 256, 0, stream>>>(img, labels, parent, bsizes, kt);

  int bblocks = (NIMG * NBLK) / 256;           // 4096 (1 thread / 2x2 block)
  merge_kernel         <<<bblocks, 256, 0, stream>>>(labels, parent);
  compress_count_kernel<<<bblocks, 256, 0, stream>>>(labels, parent, bsizes);
  output_kernel        <<<bblocks, 256, 0, stream>>>(labels, parent, bsizes, out);
}

// Round 14
// 196.404 us; speedup vs baseline: 1.1199x; 1.0516x over previous
//
#include <hip/hip_runtime.h>
#include <math.h>
#include <string.h>

#define IMG_H   512
#define IMG_W   512
#define NPIX    (IMG_H*IMG_W)       /* 262144 = 1<<18 */
#define NIMG    16
#define NSIG    5
#define MIN_SZ  200
#define SSTR    60                  /* sIn stride (dwords) */
#define SROWS   52                  /* 50 data rows + 2 zero rows for tap pad */
#define TSTR    68                  /* t stride (dwords): room for tail prefetch */
#define KVL     20
#define KHL     24
#define NBLK    65536               /* 2x2 blocks per image (256x256) */

typedef float f4 __attribute__((ext_vector_type(4)));

// Host-precomputed tap tables (kernarg -> s_load, off the VALU path):
//  kv[s][o][j]  = k_o[L-1-j], zero-padded to LP4 (vertical, pre-reversed)
//  kh[s][o][j'] = (d<=j'<d+L) ? k_o[L-1-(j'-d)]:0 (horizontal: reversed,
//                  shifted by alignment delta d=(12-RAD)&3, zero-padded)
struct KTab {
  float kv[NSIG][3][KVL];
  float kh[NSIG][3][KHL];
  float s2[NSIG];
};

// ---------------------------------------------------------------------------
// Round-9 proven conv structure (best of 13 rounds):
// Pass 1 (vertical): threads tid < 32*GH own (row r0, 8-col pair slot).
//   4-tap chunks: 3x s_load_dwordx4 weights + 8x ds_read_b128 + 96 FMA per
//   chunk -> one lgkm weight-wait amortized over 96 FMAs.
// Pass 2 (horizontal): P/Q ping-pong register window, 2x-unrolled chunks,
//   all register roles compile-time. Tail prefetch reads dead in-row data.
// Vesselness epilogue: __expf (v_exp_f32, ~3 slots) instead of OCML expf
//   (~20 slots x 40 calls/thread = ~20% of all VALU work).
// ---------------------------------------------------------------------------
template<int SIG, int RAD, int MLO, int GH, int LP4, int L4P>
__device__ __forceinline__ void do_sigma(const float* __restrict__ sIn,
                                         float* __restrict__ t0,
                                         float* __restrict__ t1,
                                         float* __restrict__ t2,
                                         const KTab& kt, int tid, float* fr)
{
  // ---- pass 1: vertical conv -> t0(k0), t1(k1), t2(k2) ----
  if (tid < 32*GH) {
    int r0 = tid & 31;
    int h  = tid >> 5;                 // 8-col pair slot
    int a  = (r0 + 9 - RAD)*SSTR + 4*(MLO + 2*h);
    f4 A0={0,0,0,0}, A1={0,0,0,0}, A2={0,0,0,0};
    f4 B0={0,0,0,0}, B1={0,0,0,0}, B2={0,0,0,0};
#pragma unroll 1
    for (int jj = 0; jj < LP4/4; ++jj) {
      f4 w0 = *(const f4*)&kt.kv[SIG][0][4*jj];
      f4 w1 = *(const f4*)&kt.kv[SIG][1][4*jj];
      f4 w2 = *(const f4*)&kt.kv[SIG][2][4*jj];
#pragma unroll
      for (int u = 0; u < 4; ++u) {
        f4 xA = *(const f4*)(sIn + a);
        f4 xB = *(const f4*)(sIn + a + 4);
        a += SSTR;
        A0 += xA*w0[u]; A1 += xA*w1[u]; A2 += xA*w2[u];
        B0 += xB*w0[u]; B1 += xB*w1[u]; B2 += xB*w2[u];
      }
    }
    int tb = r0*TSTR + 4*(MLO + 2*h);
    *(f4*)(t0 + tb)     = A0; *(f4*)(t1 + tb)     = A1; *(f4*)(t2 + tb)     = A2;
    *(f4*)(t0 + tb + 4) = B0; *(f4*)(t1 + tb + 4) = B1; *(f4*)(t2 + tb + 4) = B2;
  }
  __syncthreads();

  // ---- pass 2: horizontal conv + vesselness ----
  {
    int r  = tid >> 3;
    int c0 = (tid & 7) * 4;
    int wa = r*TSTR + 4*MLO + c0;
    f4 P0 = *(const f4*)(t0 + wa);
    f4 P1 = *(const f4*)(t1 + wa);
    f4 P2 = *(const f4*)(t2 + wa);
    f4 Q0 = *(const f4*)(t0 + wa + 4);
    f4 Q1 = *(const f4*)(t1 + wa + 4);
    f4 Q2 = *(const f4*)(t2 + wa + 4);
    wa += 8;
    f4 hrr={0,0,0,0}, hrc={0,0,0,0}, hcc={0,0,0,0};
#pragma unroll 1
    for (int aa = 0; aa < L4P/8; ++aa) {
      {  // chunk 2aa: low=P, high=Q ; then P <- next group
        f4 w0 = *(const f4*)&kt.kh[SIG][0][8*aa];
        f4 w1 = *(const f4*)&kt.kh[SIG][1][8*aa];
        f4 w2 = *(const f4*)&kt.kh[SIG][2][8*aa];
#pragma unroll
        for (int b = 0; b < 4; ++b)
#pragma unroll
          for (int k = 0; k < 4; ++k) {
            int e = b + k;                       // compile-time under unroll
            float x2 = (e < 4) ? P2[e] : Q2[e-4];
            float x1 = (e < 4) ? P1[e] : Q1[e-4];
            float x0 = (e < 4) ? P0[e] : Q0[e-4];
            hrr[k] += x2 * w0[b];                // Hrr = vert k2 (.) horiz k0
            hrc[k] += x1 * w1[b];                // Hrc = vert k1 (.) horiz k1
            hcc[k] += x0 * w2[b];                // Hcc = vert k0 (.) horiz k2
          }
        P0 = *(const f4*)(t0 + wa);
        P1 = *(const f4*)(t1 + wa);
        P2 = *(const f4*)(t2 + wa);
      }
      {  // chunk 2aa+1: low=Q, high=P(new) ; then Q <- next group
        f4 w0 = *(const f4*)&kt.kh[SIG][0][8*aa+4];
        f4 w1 = *(const f4*)&kt.kh[SIG][1][8*aa+4];
        f4 w2 = *(const f4*)&kt.kh[SIG][2][8*aa+4];
#pragma unroll
        for (int b = 0; b < 4; ++b)
#pragma unroll
          for (int k = 0; k < 4; ++k) {
            int e = b + k;
            float x2 = (e < 4) ? Q2[e] : P2[e-4];
            float x1 = (e < 4) ? Q1[e] : P1[e-4];
            float x0 = (e < 4) ? Q0[e] : P0[e-4];
            hrr[k] += x2 * w0[b];
            hrc[k] += x1 * w1[b];
            hcc[k] += x0 * w2[b];
          }
        Q0 = *(const f4*)(t0 + wa + 4);
        Q1 = *(const f4*)(t1 + wa + 4);
        Q2 = *(const f4*)(t2 + wa + 4);
      }
      wa += 8;
    }
    float s2v = kt.s2[SIG];
#pragma unroll
    for (int k = 0; k < 4; ++k) {
      float Hrr = hrr[k]*s2v, Hrc = hrc[k]*s2v, Hcc = hcc[k]*s2v;
      float mid  = 0.5f*(Hrr + Hcc);
      float dif  = 0.5f*(Hrr - Hcc);
      float disc = sqrtf(dif*dif + Hrc*Hrc);
      float ehi  = mid + disc;
      float elo  = mid - disc;
      bool  sm   = fabsf(ehi) <= fabsf(elo);
      float lam1 = sm ? ehi : elo;
      float lam2 = sm ? elo : ehi;
      float lam2c = fmaxf(lam2, 1e-10f);
      float q    = lam1 / lam2c;
      float rb2  = q*q;
      float ssq  = lam1*lam1 + lam2*lam2;
      float v    = __expf((-rb2)/2.0f) * (1.0f - __expf((-ssq)/50.0f));
      fr[k] = fmaxf(fr[k], v);
    }
  }
  __syncthreads();                     // t arrays free for next sigma
}

__global__ __launch_bounds__(256)
void frangi_label_kernel(const float* __restrict__ img,
                         int* __restrict__ labels,
                         int* __restrict__ parent,
                         int* __restrict__ bsizes,
                         KTab kt)
{
  __shared__ float sIn[SROWS*SSTR];    // 12480 B
  __shared__ float t0[32*TSTR];        // 8704 B x3
  __shared__ float t1[32*TSTR];
  __shared__ float t2[32*TSTR];

  const int tid    = threadIdx.x;
  const int imgIdx = blockIdx.y;
  const int tIdx   = blockIdx.x;
  const int tr0    = (tIdx >> 4) * 32;
  const int tc0    = (tIdx & 15) * 32;
  const float* __restrict__ im = img + (size_t)imgIdx * NPIX;

  // fill sIn: zeros outside rows [0,50) x cs [3,53);
  // inside: reflect('symmetric') + negate/scale.
  for (int idx = tid; idx < SROWS*64; idx += 256) {
    int r  = idx >> 6;
    int cs = idx & 63;
    if (cs < SSTR) {
      float v = 0.0f;
      if (r < 50 && cs >= 3 && cs < 53) {
        int gr = tr0 + r - 9;
        int gc = tc0 + cs - 12;
        gr = (gr < 0) ? (-1 - gr) : ((gr >= IMG_H) ? (2*IMG_H - 1 - gr) : gr);
        gc = (gc < 0) ? (-1 - gc) : ((gc >= IMG_W) ? (2*IMG_W - 1 - gc) : gc);
        v = -(im[gr*IMG_W + gc] * 500.0f);
      }
      sIn[r*SSTR + cs] = v;
    }
  }
  __syncthreads();

  float fr[4] = {0.0f, 0.0f, 0.0f, 0.0f};
  //        SIG RAD MLO GH LP4 L4P
  do_sigma<0,  4,  2,  6, 12, 16>(sIn, t0, t1, t2, kt, tid, fr);  // s=1.0,L=9
  do_sigma<1,  5,  1,  6, 12, 16>(sIn, t0, t1, t2, kt, tid, fr);  // s=1.3,L=11
  do_sigma<2,  6,  1,  6, 16, 16>(sIn, t0, t1, t2, kt, tid, fr);  // s=1.6,L=13
  do_sigma<3,  8,  1,  7, 20, 24>(sIn, t0, t1, t2, kt, tid, fr);  // s=1.9,L=17
  do_sigma<4,  9,  0,  7, 20, 24>(sIn, t0, t1, t2, kt, tid, fr);  // s=2.2,L=19

  const int r  = tid >> 3;
  const int c0 = (tid & 7) * 4;
  const int gr = tr0 + r;
  const size_t imgBase = (size_t)imgIdx * NPIX;
#pragma unroll
  for (int k = 0; k < 4; ++k) {
    int p = gr*IMG_W + tc0 + c0 + k;
    float x = im[p];
    bool m = (x >= 0.1f) && (x <= 0.5f) && (fr[k] >= 0.2f);
    labels[imgBase + p] = m ? p : -1;
  }
  // init 2x2-block UF arrays: thread t <-> one of the 256 tile blocks
  {
    int blk = (tr0/2 + (tid >> 4))*256 + (tc0/2 + (tid & 15));
    int o   = (imgIdx << 16) + blk;
    parent[o] = blk;
    bsizes[o] = 0;
  }
}

// ---------------------------------------------------------------------------
// BUF: 8-connected CCL over 2x2 blocks (all 4 px of a block are mutually
// 8-adjacent, so block-level UF yields exactly the pixel components).
// ---------------------------------------------------------------------------
__device__ __forceinline__ int ldA(const int* p) {
  return __hip_atomic_load(p, __ATOMIC_RELAXED, __HIP_MEMORY_SCOPE_AGENT);
}
__device__ __forceinline__ int rootOf(const int* L, int x) {
  int pa = ldA(&L[x]);
  while (pa != x) { int g = ldA(&L[pa]); x = pa; pa = g; }
  return x;
}
__device__ __forceinline__ void unite(int* P, int a, int b) {
  while (true) {
    a = rootOf(P, a);
    b = rootOf(P, b);
    if (a == b) return;
    int hi = a > b ? a : b;
    int lo = a ^ b ^ hi;
    int old = atomicCAS(&P[hi], hi, lo);
    if (old == hi) return;
    a = old; b = lo;
  }
}

__global__ __launch_bounds__(256)
void merge_kernel(const int* __restrict__ labels, int* __restrict__ parent)
{
  int gid = blockIdx.x*256 + threadIdx.x;      // one thread per 2x2 block
  int img = gid >> 16;
  int blk = gid & (NBLK - 1);
  int BR = blk >> 8, BC = blk & 255;
  const int* L = labels + ((size_t)img << 18);
  int p = BR*1024 + BC*2;                      // top-left pixel of block
  int2 t = *(const int2*)(L + p);              // l00,l01
  int2 bm = *(const int2*)(L + p + 512);       // l10,l11
  bool f00 = t.x >= 0, f01 = t.y >= 0, f10 = bm.x >= 0, f11 = bm.y >= 0;
  if (!(f00 | f01 | f10 | f11)) return;
  int* P = parent + (img << 16);
  // W: our left col vs their right col (all cross pairs are 8-adjacent)
  if (BC > 0 && (f00 | f10) && (L[p-1] >= 0 || L[p+511] >= 0))
    unite(P, blk, blk-1);
  if (BR > 0) {
    int2 n = *(const int2*)(L + p - 512);      // their bottom row
    if ((f00 | f01) && (n.x >= 0 || n.y >= 0)) unite(P, blk, blk-256);
    if (BC > 0   && f00 && L[p-513] >= 0)      unite(P, blk, blk-257);
    if (BC < 255 && f01 && L[p-510] >= 0)      unite(P, blk, blk-255);
  }
}

// compress block roots + accumulate component pixel counts.
// Wave segmented scan (flag-propagating) -> ~1 atomic per run.
__global__ __launch_bounds__(256)
void compress_count_kernel(const int* __restrict__ labels,
                           int* __restrict__ parent, int* __restrict__ bsizes)
{
  int gid = blockIdx.x*256 + threadIdx.x;
  int img = gid >> 16;
  int blk = gid & (NBLK - 1);
  int BR = blk >> 8, BC = blk & 255;
  const int* L = labels + ((size_t)img << 18);
  int p = BR*1024 + BC*2;
  int2 t = *(const int2*)(L + p);
  int2 bm = *(const int2*)(L + p + 512);
  int cnt = (t.x >= 0) + (t.y >= 0) + (bm.x >= 0) + (bm.y >= 0);
  int* P = parent + (img << 16);
  int rt = -1;
  if (cnt) {
    rt = rootOf(P, blk);
    __hip_atomic_store(&P[blk], rt, __ATOMIC_RELAXED, __HIP_MEMORY_SCOPE_AGENT);
  }
  int lane = threadIdx.x & 63;
  int val  = cnt;
  int prt  = __shfl_up(rt, 1);
  int fseg = (lane == 0 || prt != rt) ? 1 : 0;
#pragma unroll
  for (int d = 1; d < 64; d <<= 1) {
    int v2  = __shfl_up(val, d);
    int fg2 = __shfl_up(fseg, d);
    if (lane >= d && !fseg) { val += v2; fseg |= fg2; }
  }
  int nrt = __shfl_down(rt, 1);
  bool tail = (lane == 63) || (nrt != rt);
  if (tail && rt >= 0)
    atomicAdd(&bsizes[(img << 16) + rt], val);
}

__global__ __launch_bounds__(256)
void output_kernel(const int* __restrict__ labels, const int* __restrict__ parent,
                   const int* __restrict__ bsizes, float* __restrict__ out)
{
  int qid = blockIdx.x*256 + threadIdx.x;      // 4 px in a row = 2 blocks
  int img = qid >> 16;
  int p0  = (qid & 65535) << 2;
  const int* L = labels + ((size_t)img << 18);
  int4 l4 = *(const int4*)(L + p0);
  int r = p0 >> 9, c = p0 & 511;
  int blk0 = (r >> 1)*256 + (c >> 1);
  const int* P = parent + (img << 16);
  const int* S = bsizes + (img << 16);
  int2 pp = *(const int2*)(P + blk0);
  float4 o;
  o.x = (l4.x >= 0 && S[pp.x] >= MIN_SZ) ? 1.0f : 0.0f;
  o.y = (l4.y >= 0 && S[pp.x] >= MIN_SZ) ? 1.0f : 0.0f;
  o.z = (l4.z >= 0 && S[pp.y] >= MIN_SZ) ? 1.0f : 0.0f;
  o.w = (l4.w >= 0 && S[pp.y] >= MIN_SZ) ? 1.0f : 0.0f;
  *(float4*)(out + ((size_t)qid << 2)) = o;
}

// ---------------------------------------------------------------------------
// Host: scipy.ndimage-style Gaussian derivative kernels (truncate=4).
// ---------------------------------------------------------------------------
static void gauss1d(double sigma, int order, int rad, float* out)
{
  int L = 2*rad + 1;
  double phi[24];
  double s = 0.0;
  for (int i = 0; i < L; ++i) {
    double x = (double)(i - rad);
    phi[i] = exp(-0.5*x*x/(sigma*sigma));
    s += phi[i];
  }
  for (int i = 0; i < L; ++i) phi[i] /= s;
  if (order == 0) {
    for (int i = 0; i < L; ++i) out[i] = (float)phi[i];
    return;
  }
  double q[3] = {1.0, 0.0, 0.0};
  for (int it = 0; it < order; ++it) {
    double nq[3] = {0.0, 0.0, 0.0};
    for (int i = 0; i <= order; ++i) {
      double v = 0.0;
      if (i+1 <= order) v += (double)(i+1) * q[i+1];
      if (i-1 >= 0)     v += (-1.0/(sigma*sigma)) * q[i-1];
      nq[i] = v;
    }
    q[0] = nq[0]; q[1] = nq[1]; q[2] = nq[2];
  }
  for (int i = 0; i < L; ++i) {
    double x = (double)(i - rad);
    double poly = q[0];
    double xp = x;
    for (int e = 1; e <= order; ++e) { poly += xp*q[e]; xp *= x; }
    out[i] = (float)(poly*phi[i]);
  }
}

extern "C" void kernel_launch(void* const* d_in, const int* in_sizes, int n_in,
                              void* d_out, int out_size, void* d_ws, size_t ws_size,
                              hipStream_t stream)
{
  (void)in_sizes; (void)n_in; (void)out_size; (void)ws_size;
  const float* img = (const float*)d_in[0];
  float* out = (float*)d_out;
  // ws: labels 16MB | parent 4MB | bsizes 4MB
  int* labels = (int*)d_ws;
  int* parent = labels + (size_t)NIMG * NPIX;
  int* bsizes = parent + (size_t)NIMG * NBLK;

  KTab kt;
  memset(&kt, 0, sizeof(kt));
  for (int s = 0; s < NSIG; ++s) {
    double sigma = 1.0 + 0.3 * (double)s;
    int rad = (int)(4.0 * sigma + 0.5);        // 4,5,6,8,9
    int L   = 2*rad + 1;
    int dlt = (12 - rad) & 3;
    kt.s2[s] = (float)(sigma * sigma);
    float k[3][24];
    for (int o = 0; o < 3; ++o) gauss1d(sigma, o, rad, k[o]);
    for (int o = 0; o < 3; ++o) {
      for (int j = 0; j < L; ++j)
        kt.kv[s][o][j] = k[o][L-1-j];          // kv[L..] stay 0 (pad)
      for (int jp = 0; jp < KHL; ++jp)
        kt.kh[s][o][jp] = (jp >= dlt && jp - dlt < L) ? k[o][L-1-(jp-dlt)] : 0.0f;
    }
  }

  dim3 gridF(NPIX / (32*32), NIMG);            // 256 tiles x 16 images
  frangi_label_kernel<<<gridF, 256, 0, stream>>>(img, labels, parent, bsizes, kt);

  int bblocks = (NIMG * NBLK) / 256;           // 4096 (1 thread / 2x2 block)
  merge_kernel         <<<bblocks, 256, 0, stream>>>(labels, parent);
  compress_count_kernel<<<bblocks, 256, 0, stream>>>(labels, parent, bsizes);
  output_kernel        <<<bblocks, 256, 0, stream>>>(labels, parent, bsizes, out);
}